// Round 6
// baseline (365.926 us; speedup 1.0000x reference)
//
#include <hip/hip_runtime.h>
#include <hip/hip_bf16.h>

// Problem constants
#define NOUT  4096
#define KDIM  1024   // N_SPARSE
#define MROWS 8192   // BATCH*SEQ

typedef __attribute__((ext_vector_type(8))) short bf16x8;    // 8 bf16 = 4 VGPRs
typedef __attribute__((ext_vector_type(16))) float f32x16;   // MFMA 32x32 accumulator

__device__ __forceinline__ unsigned short f2bf(float f) {
  union { float f; unsigned int u; } c; c.f = f;
  unsigned int lsb = (c.u >> 16) & 1u;
  c.u += 0x7fffu + lsb;
  return (unsigned short)(c.u >> 16);
}

__device__ __forceinline__ unsigned cvtpk(float lo, float hi) {
  unsigned r;
  asm("v_cvt_pk_bf16_f32 %0, %1, %2" : "=v"(r) : "v"(lo), "v"(hi));
  return r;  // low16 = bf16(lo), high16 = bf16(hi), RNE
}

__device__ __forceinline__ void gload_lds16(const void* g, void* l) {
  __builtin_amdgcn_global_load_lds(
      (const __attribute__((address_space(1))) void*)g,
      (__attribute__((address_space(3))) void*)l, 16, 0, 0);
}

#define FENCE() asm volatile("" ::: "memory")
#define BAR() do { FENCE(); __builtin_amdgcn_s_barrier(); FENCE(); } while (0)
#define VMW(n) asm volatile("s_waitcnt vmcnt(" #n ")" ::: "memory")
#define LGKM0() asm volatile("s_waitcnt lgkmcnt(0)" ::: "memory")

// ---------------------------------------------------------------------------
// Tiny pass: sparse_values [4096,1024] f32 -> bf16 (K-contiguous)
// ---------------------------------------------------------------------------
__global__ __launch_bounds__(512) void prep_w(const float* __restrict__ w,
                                              unsigned short* __restrict__ wb) {
  const int i0 = blockIdx.x * 1024 + threadIdx.x;
#pragma unroll
  for (int j = 0; j < 2; ++j) {
    const int i = i0 + 512 * j;
    float4 v = ((const float4*)w)[i];
    ushort4 o;
    o.x = f2bf(v.x); o.y = f2bf(v.y); o.z = f2bf(v.z); o.w = f2bf(v.w);
    ((ushort4*)wb)[i] = o;
  }
}

// ---------------------------------------------------------------------------
// Fused gather+GEMM: C[m,n] = sum_k x[m, idx[k]] * W[n,k].
// 256x256 8-phase, v_mfma_f32_32x32x16_bf16, 8 waves (2Mx4N), BK=64.
// A-staging is fused: scattered f32 gathers (issued 2 phases early, T14)
// -> cvt_pk bf16 -> ds_write into the same swizzled LDS layout as round 5
// (gather k-octet = cg inverse-swizzle; LDS linear; ds_read side unchanged).
// B-staging unchanged (global_load_lds, pre-swizzled source).
// VMEM gates: VMW(36) at P4/P8 = loads issued in the protected window;
// guarantees all older VMEM (prev B-stages) retired. Gather waits are
// compiler-inserted (register consumers).
// XCD map: all 16 bn-blocks of one bm on one XCD -> x fetched from HBM once,
// 16x reuse via that XCD's private L2 (per-K-step working set ~512 KB).
// ---------------------------------------------------------------------------
__global__ __launch_bounds__(512, 2) void gemmf(const float* __restrict__ x,
                                                const void* __restrict__ idx_raw,
                                                const unsigned short* __restrict__ Bw,
                                                float* __restrict__ C) {
  __shared__ __align__(16) unsigned short lds[65536 + 2048];  // 128 KiB + 4 KiB idx
  int* sidxB = (int*)(lds + 65536);                           // byte offsets

  const int tid = threadIdx.x;
  const int lane = tid & 63;
  const int wid = tid >> 6;
  const int wm = wid >> 2, wn = wid & 3;       // 2 x 4 wave grid
  const int l31 = lane & 31, lh = lane >> 5;   // 32x32 frag: row, k-half

  // XCD-grouped tile map: xcd = bid&7 owns bm in [xcd*4, xcd*4+4), all bn.
  const int bid = blockIdx.x;
  const int bm0 = ((bid & 7) * 4 + (bid >> 7)) * 256;
  const int bn0 = ((bid >> 3) & 15) * 256;

  // ---- staging map (identical involution to round 5): thread t owns linear
  // LDS 16B slot t per 64-row region; it holds global k-octet cg of row pr.
  const int pr = tid >> 3;                                   // 0..63
  const int cg = (tid & 7) ^ (pr & 7) ^ ((pr >> 3) & 3);     // gathered k-octet
  const unsigned short* Bg = Bw + (size_t)(bn0 + pr) * KDIM + cg * 8;
  const int tid8 = tid * 8;
  const char* xb = (const char*)(x + (size_t)bm0 * 4096);

  // ---- idx table: byte offsets into an x row. int32/int64 detect: for int32
  // data, element0-as-int64 = idx0|(idx1<<32) >= 2^32 (sorted unique).
  {
    const long long* p64 = (const long long*)idx_raw;
    const int* p32 = (const int*)idx_raw;
    const bool is64 = ((unsigned long long)p64[0]) < 4096ull;
    if (is64) {
      sidxB[tid] = ((int)p64[tid]) << 2;
      sidxB[tid + 512] = ((int)p64[tid + 512]) << 2;
    } else {
      sidxB[tid] = p32[tid] << 2;
      sidxB[tid + 512] = p32[tid + 512] << 2;
    }
  }
  LGKM0(); BAR();

  // ---- ds_read map (unchanged from round 5)
  const int sw8 = (l31 & 7) ^ (l31 >> 3);
  const int cK0 = (lh ^ sw8) * 8;
  const int cK1 = cK0 ^ 16;
  const int cK2 = cK0 ^ 32;
  const int cK3 = cK0 ^ 48;
  const int aRow = wm * 8192 + l31 * 64;
  const int bRow = 32768 + wn * 4096 + l31 * 64;

  f32x16 acc[4][2] = {};
  bf16x8 a[2][4], bN0[4], bN1[4];
  float gE0[16], gE1[16], gO0[16], gO1[16];

#define LDX(boff) (*(const float*)(xb + (boff)))

#define GA_ISSUE(T, H, S) do {                                                    \
    const int _kb = (T) * 64 + cg * 8;                                            \
    const int4 _o1 = *(const int4*)&sidxB[_kb];                                   \
    const int4 _o2 = *(const int4*)&sidxB[_kb + 4];                               \
    const int _r1 = ((H) * 128 + pr) << 14;                                       \
    const int _r2 = _r1 + (64 << 14);                                             \
    S[0] = LDX(_r1 + _o1.x);  S[1] = LDX(_r1 + _o1.y);                            \
    S[2] = LDX(_r1 + _o1.z);  S[3] = LDX(_r1 + _o1.w);                            \
    S[4] = LDX(_r1 + _o2.x);  S[5] = LDX(_r1 + _o2.y);                            \
    S[6] = LDX(_r1 + _o2.z);  S[7] = LDX(_r1 + _o2.w);                            \
    S[8] = LDX(_r2 + _o1.x);  S[9] = LDX(_r2 + _o1.y);                            \
    S[10] = LDX(_r2 + _o1.z); S[11] = LDX(_r2 + _o1.w);                           \
    S[12] = LDX(_r2 + _o2.x); S[13] = LDX(_r2 + _o2.y);                           \
    S[14] = LDX(_r2 + _o2.z); S[15] = LDX(_r2 + _o2.w);                           \
  } while (0)

#define GA_WRITE(D, H, S) do {                                                    \
    uint4 _u1, _u2;                                                               \
    _u1.x = cvtpk(S[0], S[1]);   _u1.y = cvtpk(S[2], S[3]);                       \
    _u1.z = cvtpk(S[4], S[5]);   _u1.w = cvtpk(S[6], S[7]);                       \
    _u2.x = cvtpk(S[8], S[9]);   _u2.y = cvtpk(S[10], S[11]);                     \
    _u2.z = cvtpk(S[12], S[13]); _u2.w = cvtpk(S[14], S[15]);                     \
    *(uint4*)(lds + (D) * 16384 + (H) * 8192 + tid8) = _u1;                       \
    *(uint4*)(lds + (D) * 16384 + (H) * 8192 + 4096 + tid8) = _u2;                \
  } while (0)

#define STAGE_B(D, T, H) do {                                                     \
    gload_lds16(Bg + (size_t)((H) * 128) * KDIM + (T) * 64,                       \
                lds + 32768 + (D) * 16384 + (H) * 8192 + tid8);                   \
    gload_lds16(Bg + (size_t)((H) * 128 + 64) * KDIM + (T) * 64,                  \
                lds + 32768 + (D) * 16384 + (H) * 8192 + 4096 + tid8);            \
  } while (0)

#define LOAD_A(D, MH) do {                                                        \
    const unsigned short* _p = lds + (D) * 16384 + aRow + (MH) * 4096;            \
    a[0][0] = *(const bf16x8*)(_p + cK0);        a[0][1] = *(const bf16x8*)(_p + cK1);         \
    a[0][2] = *(const bf16x8*)(_p + cK2);        a[0][3] = *(const bf16x8*)(_p + cK3);         \
    a[1][0] = *(const bf16x8*)(_p + 2048 + cK0); a[1][1] = *(const bf16x8*)(_p + 2048 + cK1);  \
    a[1][2] = *(const bf16x8*)(_p + 2048 + cK2); a[1][3] = *(const bf16x8*)(_p + 2048 + cK3);  \
  } while (0)

#define LOAD_B(D, NF, R) do {                                                     \
    const unsigned short* _p = lds + (D) * 16384 + bRow + (NF) * 2048;            \
    R[0] = *(const bf16x8*)(_p + cK0); R[1] = *(const bf16x8*)(_p + cK1);         \
    R[2] = *(const bf16x8*)(_p + cK2); R[3] = *(const bf16x8*)(_p + cK3);         \
  } while (0)

#define MFMA_Q(MH, NH, R) do {                                                    \
    __builtin_amdgcn_s_setprio(1);                                                \
    _Pragma("unroll") for (int kb = 0; kb < 4; ++kb) {                            \
      _Pragma("unroll") for (int mf = 0; mf < 2; ++mf) {                          \
        acc[(MH)*2+mf][NH] = __builtin_amdgcn_mfma_f32_32x32x16_bf16(             \
            a[mf][kb], R[kb], acc[(MH)*2+mf][NH], 0, 0, 0);                       \
      }                                                                           \
    }                                                                             \
    __builtin_amdgcn_s_setprio(0);                                                \
  } while (0)

  // ---- prologue: tile0 fully into buf0; tile1's A-gathers + B-stage in flight.
  GA_ISSUE(0, 0, gE0); GA_ISSUE(0, 1, gE1);
  STAGE_B(0, 0, 0); STAGE_B(0, 0, 1);
  GA_WRITE(0, 0, gE0);   // compiler-inserted vmcnt waits for the gathers
  GA_WRITE(0, 1, gE1);
  VMW(0);                // buf0-B landed (drains only old loads)
  GA_ISSUE(1, 0, gO0); STAGE_B(1, 1, 0);
  GA_ISSUE(1, 1, gO1); STAGE_B(1, 1, 1);   // 36 VMEM in flight
  LGKM0(); BAR();

  // ---- main loop: iter i computes tiles 2i (buf0, P1-P4), 2i+1 (buf1, P5-P8).
  // A: issued P3/P4 (tile tN0 -> buf0, written P5/P6), P7/P8 (tN1 -> buf1,
  // written next P1/P2). B: gload_lds at P3/P4 (buf0) and P7/P8 (buf1).
  // Gates: VMW(36) at P4/P8 -> everything older than the last 2 phases retired.
  for (int i = 0; i < 8; ++i) {
    const int tN0 = (2 * i + 2) & 15;
    const int tN1 = (2 * i + 3) & 15;

    // P1
    LOAD_A(0, 0); LOAD_B(0, 0, bN0); GA_WRITE(1, 0, gO0); LGKM0();
    BAR(); MFMA_Q(0, 0, bN0); BAR();
    // P2
    LOAD_B(0, 1, bN1); GA_WRITE(1, 1, gO1); LGKM0();
    BAR(); MFMA_Q(0, 1, bN1); BAR();
    // P3
    LOAD_A(0, 1); GA_ISSUE(tN0, 0, gE0); STAGE_B(0, tN0, 0);
    BAR(); MFMA_Q(1, 0, bN0); BAR();
    // P4 (gate: buf1-B from prev P7/P8 retired before P5/P6 reads)
    GA_ISSUE(tN0, 1, gE1); STAGE_B(0, tN0, 1);
    BAR(); MFMA_Q(1, 1, bN1); VMW(36); BAR();
    // P5
    LOAD_A(1, 0); LOAD_B(1, 0, bN0); GA_WRITE(0, 0, gE0); LGKM0();
    BAR(); MFMA_Q(0, 0, bN0); BAR();
    // P6
    LOAD_B(1, 1, bN1); GA_WRITE(0, 1, gE1); LGKM0();
    BAR(); MFMA_Q(0, 1, bN1); BAR();
    // P7
    LOAD_A(1, 1); GA_ISSUE(tN1, 0, gO0); STAGE_B(1, tN1, 0);
    BAR(); MFMA_Q(1, 0, bN0); BAR();
    // P8 (gate: buf0-B from P3/P4 retired before next P1/P2 reads)
    GA_ISSUE(tN1, 1, gO1); STAGE_B(1, tN1, 1);
    BAR(); MFMA_Q(1, 1, bN1); VMW(36); BAR();
  }

  // ---- epilogue. 32x32 C/D (m74/m101): col = lane&31,
  // row = (reg&3) + 8*(reg>>2) + 4*(lane>>5).
  VMW(0);
  float* base = C + (size_t)(bm0 + wm * 128) * NOUT + bn0 + wn * 64;
#pragma unroll
  for (int mf = 0; mf < 4; ++mf)
#pragma unroll
    for (int nf = 0; nf < 2; ++nf) {
      f32x16 v = acc[mf][nf];
#pragma unroll
      for (int r = 0; r < 16; ++r) {
        const int rowi = mf * 32 + (r & 3) + 8 * (r >> 2) + 4 * lh;
        base[(size_t)rowi * NOUT + nf * 32 + l31] = v[r];
      }
    }

#undef LDX
#undef GA_ISSUE
#undef GA_WRITE
#undef STAGE_B
#undef LOAD_A
#undef LOAD_B
#undef MFMA_Q
}

extern "C" void kernel_launch(void* const* d_in, const int* in_sizes, int n_in,
                              void* d_out, int out_size, void* d_ws, size_t ws_size,
                              hipStream_t stream) {
  const float* x   = (const float*)d_in[0];   // [4,2048,4096] f32
  const float* sv  = (const float*)d_in[1];   // [4096,1024] f32
  const void*  idx = d_in[2];                 // [1024] int32 or int64
  float* out = (float*)d_out;                 // [4,2048,4096] f32

  unsigned short* wb = (unsigned short*)d_ws; // [4096,1024] bf16

  prep_w<<<1024, 512, 0, stream>>>(sv, wb);
  gemmf<<<512, 512, 0, stream>>>(x, idx, wb, out);
}

// Round 7
// 113.577 us; speedup vs baseline: 3.2218x; 3.2218x over previous
//
#include <hip/hip_runtime.h>
#include <hip/hip_bf16.h>

// Problem constants
#define NOUT  4096
#define KDIM  1024   // N_SPARSE
#define MROWS 8192   // BATCH*SEQ

typedef __attribute__((ext_vector_type(8))) short bf16x8;    // 8 bf16 = 4 VGPRs
typedef __attribute__((ext_vector_type(16))) float f32x16;   // MFMA 32x32 accumulator

__device__ __forceinline__ unsigned short f2bf(float f) {
  union { float f; unsigned int u; } c; c.f = f;
  unsigned int lsb = (c.u >> 16) & 1u;
  c.u += 0x7fffu + lsb;
  return (unsigned short)(c.u >> 16);
}

__device__ __forceinline__ void gload_lds16(const void* g, void* l) {
  __builtin_amdgcn_global_load_lds(
      (const __attribute__((address_space(1))) void*)g,
      (__attribute__((address_space(3))) void*)l, 16, 0, 0);
}

#define FENCE() asm volatile("" ::: "memory")
#define BAR() do { FENCE(); __builtin_amdgcn_s_barrier(); FENCE(); } while (0)
#define VMW(n) asm volatile("s_waitcnt vmcnt(" #n ")" ::: "memory")
#define LGKM0() asm volatile("s_waitcnt lgkmcnt(0)" ::: "memory")

// ---------------------------------------------------------------------------
// Pass 1 (round-3 variant, measured best ~33 us): blocks [0,2048) gather+
// convert 4 x-rows each via LDS row staging; blocks [2048,2560) convert W.
// ---------------------------------------------------------------------------
__global__ __launch_bounds__(512) void prep(const float* __restrict__ x,
                                            const void* __restrict__ idx_raw,
                                            const float* __restrict__ w,
                                            unsigned short* __restrict__ xg,
                                            unsigned short* __restrict__ wb) {
  __shared__ float rows[16384];   // 64 KiB: 4 rows of 4096 f32
  __shared__ int sidx[1024];
  const int b = blockIdx.x;
  const int t = threadIdx.x;

  if (b < 2048) {
    const long long* p64 = (const long long*)idx_raw;
    const int* p32 = (const int*)idx_raw;
    // int64 vs int32 detection: for int32 data, element0-as-int64 >= 2^32
    // (sorted unique indices, second word >= 1), so `< 4096` discriminates.
    const bool is64 = ((unsigned long long)p64[0]) < 4096ull;
    const float* src = x + (size_t)b * 4 * 4096;
#pragma unroll
    for (int i = 0; i < 8; ++i)
      ((float4*)rows)[t + 512 * i] = ((const float4*)src)[t + 512 * i];
    if (is64) {
      sidx[t] = (int)p64[t];
      sidx[t + 512] = (int)p64[t + 512];
    } else {
      sidx[t] = p32[t];
      sidx[t + 512] = p32[t + 512];
    }
    __syncthreads();
    ushort4* dst = (ushort4*)(xg + (size_t)b * 4 * 1024);
#pragma unroll
    for (int i = 0; i < 2; ++i) {
      const int q = t + 512 * i;      // ushort4 index within 4 output rows
      const int e = 4 * q;
      const int rbase = (e >> 10) * 4096;
      const int k = e & 1023;
      ushort4 o;
      o.x = f2bf(rows[rbase + sidx[k + 0]]);
      o.y = f2bf(rows[rbase + sidx[k + 1]]);
      o.z = f2bf(rows[rbase + sidx[k + 2]]);
      o.w = f2bf(rows[rbase + sidx[k + 3]]);
      dst[q] = o;
    }
  } else {
    const int i0 = (b - 2048) * 2048 + t;
#pragma unroll
    for (int j = 0; j < 4; ++j) {
      float4 v = ((const float4*)w)[i0 + 512 * j];
      ushort4 o;
      o.x = f2bf(v.x); o.y = f2bf(v.y); o.z = f2bf(v.z); o.w = f2bf(v.w);
      ((ushort4*)wb)[i0 + 512 * j] = o;
    }
  }
}

// ---------------------------------------------------------------------------
// Pass 2: 256x256 8-phase bf16 GEMM on v_mfma_f32_32x32x16_bf16.
// Identical to the verified round-5 kernel EXCEPT the last iteration is
// peeled: tiles 14/15 run barrier-free with each output quadrant's stores
// issued right after its final MFMA, so the C-write drains under the
// remaining quadrants' compute instead of in a serial epilogue tail.
// (Also removes round-5's redundant i=7 restage of tiles 0/1.)
//   A: [8192,1024] bf16 row-major, B: [4096,1024] bf16 row-major, C: f32.
// Swizzle: granule(row,chunk) = chunk ^ (row&7) ^ ((row>>3)&3), applied on
// global source + ds_read address, LDS dest linear (rule #21); measured
// conflict-free. VMW(4) gates at P4/P8 only.
// ---------------------------------------------------------------------------
__global__ __launch_bounds__(512, 2) void gemm256(const unsigned short* __restrict__ A,
                                                  const unsigned short* __restrict__ B,
                                                  float* __restrict__ C) {
  __shared__ __align__(16) unsigned short lds[65536];  // 128 KiB

  const int tid = threadIdx.x;
  const int lane = tid & 63;
  const int wid = tid >> 6;
  const int wm = wid >> 2, wn = wid & 3;       // 2 x 4 wave grid
  const int l31 = lane & 31, lh = lane >> 5;   // 32x32 frag: row, k-half

  const int bn0 = blockIdx.x * 256;
  const int bm0 = blockIdx.y * 256;

  // ---- staging map: thread t owns linear LDS 16B slot t per 64-row region;
  // region row r = t>>3, granule g = t&7 holds global k-octet
  // c = g ^ (r&7) ^ ((r>>3)&3).
  const int pr = tid >> 3;
  const int cg = (tid & 7) ^ (pr & 7) ^ ((pr >> 3) & 3);
  const unsigned short* Ag = A + (size_t)(bm0 + pr) * KDIM + cg * 8;
  const unsigned short* Bg = B + (size_t)(bn0 + pr) * KDIM + cg * 8;
  const int tid8 = tid * 8;

  // ---- ds_read map: element (row R, k-octet c) at ushort offset
  // R*64 + (c ^ (R&7) ^ ((R>>3)&3)) * 8 within a tile.
  const int sw8 = (l31 & 7) ^ (l31 >> 3);
  const int cK0 = (lh ^ sw8) * 8;
  const int cK1 = cK0 ^ 16;
  const int cK2 = cK0 ^ 32;
  const int cK3 = cK0 ^ 48;
  const int aRow = wm * 8192 + l31 * 64;
  const int bRow = 32768 + wn * 4096 + l31 * 64;

  f32x16 acc[4][2] = {};
  bf16x8 a[2][4], bN0[4], bN1[4];

#define LOAD_A(D, MH) do {                                                        \
    const unsigned short* _p = lds + (D) * 16384 + aRow + (MH) * 4096;            \
    a[0][0] = *(const bf16x8*)(_p + cK0);        a[0][1] = *(const bf16x8*)(_p + cK1);         \
    a[0][2] = *(const bf16x8*)(_p + cK2);        a[0][3] = *(const bf16x8*)(_p + cK3);         \
    a[1][0] = *(const bf16x8*)(_p + 2048 + cK0); a[1][1] = *(const bf16x8*)(_p + 2048 + cK1);  \
    a[1][2] = *(const bf16x8*)(_p + 2048 + cK2); a[1][3] = *(const bf16x8*)(_p + 2048 + cK3);  \
  } while (0)

#define LOAD_B(D, NF, R) do {                                                     \
    const unsigned short* _p = lds + (D) * 16384 + bRow + (NF) * 2048;            \
    R[0] = *(const bf16x8*)(_p + cK0); R[1] = *(const bf16x8*)(_p + cK1);         \
    R[2] = *(const bf16x8*)(_p + cK2); R[3] = *(const bf16x8*)(_p + cK3);         \
  } while (0)

#define STAGE_A(D, T, H) do {                                                     \
    gload_lds16(Ag + (size_t)((H) * 128) * KDIM + (T) * 64,                       \
                lds + (D) * 16384 + (H) * 8192 + tid8);                           \
    gload_lds16(Ag + (size_t)((H) * 128 + 64) * KDIM + (T) * 64,                  \
                lds + (D) * 16384 + (H) * 8192 + 4096 + tid8);                    \
  } while (0)

#define STAGE_B(D, T, H) do {                                                     \
    gload_lds16(Bg + (size_t)((H) * 128) * KDIM + (T) * 64,                       \
                lds + 32768 + (D) * 16384 + (H) * 8192 + tid8);                   \
    gload_lds16(Bg + (size_t)((H) * 128 + 64) * KDIM + (T) * 64,                  \
                lds + 32768 + (D) * 16384 + (H) * 8192 + 4096 + tid8);            \
  } while (0)

#define MFMA_Q(MH, NH, R) do {                                                    \
    __builtin_amdgcn_s_setprio(1);                                                \
    _Pragma("unroll") for (int kb = 0; kb < 4; ++kb) {                            \
      _Pragma("unroll") for (int mf = 0; mf < 2; ++mf) {                          \
        acc[(MH)*2+mf][NH] = __builtin_amdgcn_mfma_f32_32x32x16_bf16(             \
            a[mf][kb], R[kb], acc[(MH)*2+mf][NH], 0, 0, 0);                       \
      }                                                                           \
    }                                                                             \
    __builtin_amdgcn_s_setprio(0);                                                \
  } while (0)

  // ---- prologue: tile0 (buf0) fully + tile1 (buf1) B-halves.
  STAGE_B(0, 0, 0); STAGE_B(0, 0, 1);
  STAGE_A(0, 0, 0); STAGE_A(0, 0, 1);
  STAGE_B(1, 1, 0); STAGE_B(1, 1, 1);
  VMW(4);
  BAR();

  // ---- main loop over iterations 0..6 (tiles 0..13); tiles 14/15 peeled.
  for (int i = 0; i < 7; ++i) {
    const int tA1 = 2 * i + 1;
    const int tN0 = 2 * i + 2;
    const int tN1 = 2 * i + 3;

    // P1: buf0 (M0,N0)
    LOAD_A(0, 0); LOAD_B(0, 0, bN0); STAGE_A(1, tA1, 0);
    BAR(); MFMA_Q(0, 0, bN0); BAR();
    // P2: buf0 (M0,N1)
    LOAD_B(0, 1, bN1); STAGE_A(1, tA1, 1);
    BAR(); MFMA_Q(0, 1, bN1); BAR();
    // P3: buf0 (M1,N0)
    LOAD_A(0, 1); STAGE_B(0, tN0, 0);
    BAR(); MFMA_Q(1, 0, bN0); BAR();
    // P4: buf0 (M1,N1) + gate for buf1
    STAGE_B(0, tN0, 1);
    BAR(); MFMA_Q(1, 1, bN1); VMW(4); BAR();
    // P5: buf1 (M0,N0)
    LOAD_A(1, 0); LOAD_B(1, 0, bN0); STAGE_A(0, tN0, 0);
    BAR(); MFMA_Q(0, 0, bN0); BAR();
    // P6: buf1 (M0,N1)
    LOAD_B(1, 1, bN1); STAGE_A(0, tN0, 1);
    BAR(); MFMA_Q(0, 1, bN1); BAR();
    // P7: buf1 (M1,N0)
    LOAD_A(1, 1); STAGE_B(1, tN1, 0);
    BAR(); MFMA_Q(1, 0, bN0); BAR();
    // P8: buf1 (M1,N1) + gate for next buf0
    STAGE_B(1, tN1, 1);
    BAR(); MFMA_Q(1, 1, bN1); VMW(4); BAR();
  }

  // ---- peeled final iteration: buf0 = tile14 (fully resident after i=6's
  // P8 gate+barrier), buf1 = tile15 (B staged at i=6 P7/P8; A staged here --
  // this replaces the removed i=7 P1/P2). buf1-A's old contents (tile 13)
  // had their last read before i=6's final barrier -> safe to overwrite.
  STAGE_A(1, 15, 0); STAGE_A(1, 15, 1);

  // t14 (buf0): all four quadrants, barrier-free (reads only buf0).
  LOAD_A(0, 0); LOAD_B(0, 0, bN0); MFMA_Q(0, 0, bN0);
  LOAD_B(0, 1, bN1);               MFMA_Q(0, 1, bN1);
  LOAD_A(0, 1);                    MFMA_Q(1, 0, bN0);
                                   MFMA_Q(1, 1, bN1);

  // tile15 A+B must be fully landed in every wave before reads.
  VMW(0); LGKM0(); BAR();

  // C/D layout (m74/m101): col = lane&31, row = (reg&3) + 8*(reg>>2) + 4*lh.
  float* base = C + (size_t)(bm0 + wm * 128) * NOUT + bn0 + wn * 64;
#define STORE_Q(MH, NH) do {                                                      \
    _Pragma("unroll") for (int mf = 0; mf < 2; ++mf) {                            \
      f32x16 v = acc[(MH)*2+mf][NH];                                              \
      _Pragma("unroll") for (int r = 0; r < 16; ++r) {                            \
        const int rowi = ((MH)*2+mf) * 32 + (r & 3) + 8 * (r >> 2) + 4 * lh;      \
        base[(size_t)rowi * NOUT + (NH) * 32 + l31] = v[r];                       \
      }                                                                           \
    }                                                                             \
  } while (0)

  // t15 (buf1): each quadrant's stores issue right after its final MFMA and
  // drain under the remaining quadrants' compute.
  LOAD_A(1, 0); LOAD_B(1, 0, bN0); MFMA_Q(0, 0, bN0); STORE_Q(0, 0);
  LOAD_B(1, 1, bN1);               MFMA_Q(0, 1, bN1); STORE_Q(0, 1);
  LOAD_A(1, 1);                    MFMA_Q(1, 0, bN0); STORE_Q(1, 0);
                                   MFMA_Q(1, 1, bN1); STORE_Q(1, 1);

#undef LOAD_A
#undef LOAD_B
#undef STAGE_A
#undef STAGE_B
#undef MFMA_Q
#undef STORE_Q
}

extern "C" void kernel_launch(void* const* d_in, const int* in_sizes, int n_in,
                              void* d_out, int out_size, void* d_ws, size_t ws_size,
                              hipStream_t stream) {
  const float* x   = (const float*)d_in[0];   // [4,2048,4096] f32
  const float* sv  = (const float*)d_in[1];   // [4096,1024] f32
  const void*  idx = d_in[2];                 // [1024] int32 or int64
  float* out = (float*)d_out;                 // [4,2048,4096] f32

  unsigned short* xg = (unsigned short*)d_ws;                 // [8192,1024] bf16
  unsigned short* wb = xg + (size_t)MROWS * KDIM;             // [4096,1024] bf16

  prep<<<2560, 512, 0, stream>>>(x, idx, sv, xg, wb);

  dim3 grid(NOUT / 256, MROWS / 256);  // (16, 32) = 512 blocks
  gemm256<<<grid, 512, 0, stream>>>(xg, wb, out);
}